// Round 11
// baseline (327.057 us; speedup 1.0000x reference)
//
#include <hip/hip_runtime.h>

#define NF 768
#define D1 10
#define D2 128
#define BM 64

typedef __attribute__((ext_vector_type(8))) short bf16x8;
typedef __attribute__((ext_vector_type(16))) float f32x16;

static __device__ __forceinline__ float sigf(float v){ return 1.0f/(1.0f+__expf(-v)); }
static __device__ __forceinline__ float tanhfast(float v){ return 2.0f/(1.0f+__expf(-2.0f*v)) - 1.0f; }
static __device__ __forceinline__ short f2bf(float f){
    unsigned u = __float_as_uint(f);
    u += 0x7fffu + ((u>>16)&1u);
    return (short)(u>>16);
}

// async global->LDS, 16B per lane, LDS dest = wave-uniform base + lane*16
static __device__ __forceinline__ void gload16(const void* g, void* l){
    __builtin_amdgcn_global_load_lds(
        (const __attribute__((address_space(1))) unsigned int*)(unsigned long long)g,
        (__attribute__((address_space(3))) unsigned int*)(unsigned long long)l,
        16, 0, 0);
}

static __device__ __forceinline__ bf16x8 cvt8(float4 a, float4 b){
    unsigned u0,u1,u2,u3;
    asm("v_cvt_pk_bf16_f32 %0, %1, %2" : "=v"(u0) : "v"(a.x), "v"(a.y));
    asm("v_cvt_pk_bf16_f32 %0, %1, %2" : "=v"(u1) : "v"(a.z), "v"(a.w));
    asm("v_cvt_pk_bf16_f32 %0, %1, %2" : "=v"(u2) : "v"(b.x), "v"(b.y));
    asm("v_cvt_pk_bf16_f32 %0, %1, %2" : "=v"(u3) : "v"(b.z), "v"(b.w));
    union { unsigned u[4]; bf16x8 v; } r;
    r.u[0]=u0; r.u[1]=u1; r.u[2]=u2; r.u[3]=u3;
    return r.v;
}

// ---- degree counts ----
__global__ void k_deg(const int* __restrict__ dst, int* __restrict__ cnt, int E){
    int e = blockIdx.x*256 + threadIdx.x;
    if(e<E) atomicAdd(&cnt[dst[e]], 1);
}

// ---- scan (rowptr/rowcur) + dinv fused, single block ----
__global__ __launch_bounds__(256) void k_scan(const int* __restrict__ cnt,
                                              int* __restrict__ rowptr, int* __restrict__ rowcur,
                                              float* __restrict__ dinv, int N, int E){
    __shared__ int part[256];
    int t = threadIdx.x;
    int C = (N+255)/256;
    int lo = t*C, hi = lo+C; if(hi>N) hi=N; if(lo>N) lo=N;
    int s=0;
    for(int i=lo;i<hi;i++) s += cnt[i];
    part[t]=s;
    __syncthreads();
    if(t==0){
        int run=0;
        for(int i=0;i<256;i++){ int v=part[i]; part[i]=run; run+=v; }
        rowptr[N]=E;
    }
    __syncthreads();
    int run = part[t];
    for(int i=lo;i<hi;i++){
        rowptr[i]=run; rowcur[i]=run; run += cnt[i];
        dinv[i] = rsqrtf((float)cnt[i] + 1.0f);
    }
}

__global__ void k_fill(const int* __restrict__ src, const int* __restrict__ dst,
                       const float* __restrict__ dinv, int* __restrict__ rowcur,
                       int* __restrict__ esrc, float* __restrict__ enorm, int E){
    int e = blockIdx.x*256 + threadIdx.x;
    if(e>=E) return;
    int s=src[e], d=dst[e];
    int pos = atomicAdd(&rowcur[d], 1);
    esrc[pos]=s;
    enorm[pos]=dinv[s]*dinv[d];
}

// ---- h1 = x @ W1 ----
__global__ __launch_bounds__(256) void k_h1(const float* __restrict__ x,
                                            const float* __restrict__ W1,
                                            float* __restrict__ h1, int N){
    __shared__ float wt[D1*NF];
    for(int idx=threadIdx.x; idx<NF*D1; idx+=256){
        int k=idx/D1, c=idx-k*D1;
        wt[c*NF+k]=W1[idx];
    }
    __syncthreads();
    int row = blockIdx.x*4 + (threadIdx.x>>6);
    int lane = threadIdx.x&63;
    if(row>=N) return;
    const float4* xr = (const float4*)(x + (size_t)row*NF);
    float acc[D1];
#pragma unroll
    for(int c=0;c<D1;c++) acc[c]=0.f;
#pragma unroll
    for(int i=0;i<3;i++){
        float4 v = xr[lane + 64*i];
#pragma unroll
        for(int c=0;c<D1;c++){
            float4 w = *(const float4*)&wt[c*NF + (lane+64*i)*4];
            acc[c] += v.x*w.x + v.y*w.y + v.z*w.z + v.w*w.w;
        }
    }
#pragma unroll
    for(int c=0;c<D1;c++){
        float v=acc[c];
#pragma unroll
        for(int off=32;off;off>>=1) v += __shfl_down(v,off,64);
        acc[c]=v;
    }
    if(lane==0){
#pragma unroll
        for(int c=0;c<D1;c++) h1[(size_t)row*D1+c]=acc[c];
    }
}

// ---- layer-1 CSR gather + relu ----
__global__ __launch_bounds__(256) void k_gath1(const float* __restrict__ h1,
        const int* __restrict__ rowptr, const int* __restrict__ esrc,
        const float* __restrict__ enorm, const float* __restrict__ dinv,
        const float* __restrict__ b1, float* __restrict__ h, int N){
    int node = blockIdx.x*4 + (threadIdx.x>>6);
    int lane = threadIdx.x&63;
    if(node>=N) return;
    int e0=rowptr[node], e1=rowptr[node+1];
    float acc[D1];
#pragma unroll
    for(int c=0;c<D1;c++) acc[c]=0.f;
    for(int e=e0+lane; e<e1; e+=64){
        int s=esrc[e]; float w=enorm[e];
        const float* hr = h1 + (size_t)s*D1;
#pragma unroll
        for(int c=0;c<D1;c++) acc[c] += hr[c]*w;
    }
    if(lane==0){
        float di=dinv[node], d2=di*di;
        const float* hr = h1 + (size_t)node*D1;
#pragma unroll
        for(int c=0;c<D1;c++) acc[c] += hr[c]*d2;
    }
#pragma unroll
    for(int c=0;c<D1;c++){
        float v=acc[c];
#pragma unroll
        for(int off=32;off;off>>=1) v += __shfl_down(v,off,64);
        acc[c]=v;
    }
    if(lane==0){
#pragma unroll
        for(int c=0;c<D1;c++){
            float v = acc[c] + b1[c];
            h[(size_t)node*D1+c] = v>0.f ? v : 0.f;
        }
    }
}

__global__ __launch_bounds__(128) void k_hz(const float* __restrict__ h,
                                            const float* __restrict__ W2,
                                            float* __restrict__ hz, int N){
    __shared__ float w2s[D1*D2];
    int j = threadIdx.x;
    for(int i=j;i<D1*D2;i+=128) w2s[i]=W2[i];
    __syncthreads();
    int n = blockIdx.x;
    if(n>=N) return;
    const float* hr = h + (size_t)n*D1;
    float acc=0.f;
#pragma unroll
    for(int k=0;k<D1;k++) acc += hr[k]*w2s[k*D2+j];
    hz[(size_t)n*D2+j]=acc;
}

// ---- layer-2 CSR gather (fused zfin), writes fp32 z table ----
__global__ __launch_bounds__(128) void k_gath2(const float* __restrict__ hz,
        const int* __restrict__ rowptr, const int* __restrict__ esrc,
        const float* __restrict__ enorm, const float* __restrict__ dinv,
        const float* __restrict__ b2, float* __restrict__ zbf, int N){
    int n = blockIdx.x;
    int c = threadIdx.x;
    int e0 = rowptr[n], e1 = rowptr[n+1];
    float di = dinv[n];
    float acc = hz[(size_t)n*D2+c]*di*di + b2[c];
    int e = e0;
    for(; e+1<e1; e+=2){
        int s0=esrc[e], s1=esrc[e+1];
        float w0=enorm[e], w1=enorm[e+1];
        acc += hz[(size_t)s0*D2+c]*w0 + hz[(size_t)s1*D2+c]*w1;
    }
    if(e<e1) acc += hz[(size_t)esrc[e]*D2+c]*enorm[e];
    zbf[(size_t)n*D2+c] = acc;
}

// ---- B fragment image over FULL K=1024: 12 frags x 64 ks16 x 64 lanes x 8 bf16 ----
__global__ void k_wimgB(const float* __restrict__ Wih, ushort* __restrict__ img){
    int gid = blockIdx.x*256 + threadIdx.x;        // 12*64*64 = 49152
    if(gid >= 12*64*64) return;
    int l = gid & 63;
    int ks16 = (gid>>6) & 63;
    int f = gid >> 12;
    int dd = l & 31, kb = l>>5;
    int wn = f/3, gi = f - wn*3;
    int gbase = (gi==0)?0:((gi==1)?256:384);
    int wrow = gbase + wn*32 + dd;
    int k = ks16*16 + kb*8;
    const float* p = Wih + (size_t)wrow*1024 + k;
    float4 v0=*(const float4*)p, v1=*(const float4*)(p+4);
    bf16x8 o;
    o[0]=f2bf(v0.x); o[1]=f2bf(v0.y); o[2]=f2bf(v0.z); o[3]=f2bf(v0.w);
    o[4]=f2bf(v1.x); o[5]=f2bf(v1.y); o[6]=f2bf(v1.z); o[7]=f2bf(v1.w);
    *(bf16x8*)(img + (size_t)gid*8) = o;
}

// ---- fused MFMA GEMM + LSTM, m97 structure: single-buffered LDS, both operands
// via global_load_lds, 2 plain __syncthreads per K-step, no explicit waits.
// 32 KB LDS + (256,3) -> 3 blocks/CU; co-resident blocks cover barrier drains. ----
__global__ __launch_bounds__(256,3) void k_big(
    const float* __restrict__ remb, const ushort* __restrict__ img,
    const float* __restrict__ zbf, const float* __restrict__ b_ih,
    const float* __restrict__ b_hh, const int* __restrict__ trip,
    float* __restrict__ score, int T)
{
    __shared__ float  As[64*32];       // 8 KB: 64 rows x 32 fp32, 16B-unit XOR(row&7) swizzle
    __shared__ ushort Bs[24*64*8];     // 24 KB: (frag*2+h) x lane x 8 bf16, frag-linear
    int tid=threadIdx.x, lane=tid&63, w=tid>>6;
    int l31=lane&31, lh=lane>>5;
    int t0=blockIdx.x*BM;

    // A staging: wave w stages rows [w*16, w*16+16) as 2 x 1KB (8 rows each).
    // lane: row_local = lane>>3, unit = lane&7; source pre-swizzled by row&7.
    const int aoff = ((lane&7) ^ (lane>>3))*4;     // floats
    const float* pzh[2]; const float* prm[2]; const float* pzt[2];
#pragma unroll
    for(int j=0;j<2;j++){
        int row = w*16 + j*8 + (lane>>3);
        int tc = t0+row; if(tc>=T) tc=T-1;
        pzh[j] = zbf + (size_t)trip[3*tc]*D2   + aoff;
        prm[j] = remb + (size_t)tc*NF          + aoff;
        pzt[j] = zbf + (size_t)trip[3*tc+2]*D2 + aoff;
    }
    float* adst0 = &As[(w*16+0)*32];
    float* adst1 = &As[(w*16+8)*32];

    f32x16 acc[2][3];
    const f32x16 zer = {0,0,0,0,0,0,0,0,0,0,0,0,0,0,0,0};
#pragma unroll
    for(int m=0;m<2;m++)
#pragma unroll
        for(int g=0;g<3;g++) acc[m][g]=zer;

    const int rx7 = l31&7;

    for(int s=0;s<32;s++){
        // ---- stage feat k-slice s (32 fp): [zh 0..3 | remb 4..27 | zt 28..31] ----
        const float *sa0, *sa1;
        if(s<4)      { sa0=pzh[0]+s*32;      sa1=pzh[1]+s*32; }
        else if(s<28){ sa0=prm[0]+(s-4)*32;  sa1=prm[1]+(s-4)*32; }
        else         { sa0=pzt[0]+(s-28)*32; sa1=pzt[1]+(s-28)*32; }
        gload16(sa0, adst0);
        gload16(sa1, adst1);
        // ---- stage B tile (2 ks16 x 12 frags), 6 x 1KB per wave ----
#pragma unroll
        for(int j=0;j<6;j++){
            int f = w*3 + (j>>1), sh = j&1;
            gload16(img + ((size_t)(f*64 + s*2 + sh)*64 + lane)*8,
                    &Bs[(size_t)((f*2+sh)*64)*8]);
        }
        __syncthreads();
        // ---- compute 2 ks16 ----
#pragma unroll
        for(int h=0;h<2;h++){
            int u0 = h*4 + lh*2;
            float4 a00 = *(const float4*)&As[ l31*32     + ((u0  )^rx7)*4];
            float4 a01 = *(const float4*)&As[ l31*32     + ((u0+1)^rx7)*4];
            bf16x8 A0 = cvt8(a00,a01);
            float4 a10 = *(const float4*)&As[(32+l31)*32 + ((u0  )^rx7)*4];
            float4 a11 = *(const float4*)&As[(32+l31)*32 + ((u0+1)^rx7)*4];
            bf16x8 A1 = cvt8(a10,a11);
            bf16x8 B0 = *(const bf16x8*)&Bs[(size_t)(((w*3+0)*2+h)*64+lane)*8];
            bf16x8 B1 = *(const bf16x8*)&Bs[(size_t)(((w*3+1)*2+h)*64+lane)*8];
            bf16x8 B2 = *(const bf16x8*)&Bs[(size_t)(((w*3+2)*2+h)*64+lane)*8];
            acc[0][0]=__builtin_amdgcn_mfma_f32_32x32x16_bf16(A0,B0,acc[0][0],0,0,0);
            acc[0][1]=__builtin_amdgcn_mfma_f32_32x32x16_bf16(A0,B1,acc[0][1],0,0,0);
            acc[0][2]=__builtin_amdgcn_mfma_f32_32x32x16_bf16(A0,B2,acc[0][2],0,0,0);
            acc[1][0]=__builtin_amdgcn_mfma_f32_32x32x16_bf16(A1,B0,acc[1][0],0,0,0);
            acc[1][1]=__builtin_amdgcn_mfma_f32_32x32x16_bf16(A1,B1,acc[1][1],0,0,0);
            acc[1][2]=__builtin_amdgcn_mfma_f32_32x32x16_bf16(A1,B2,acc[1][2],0,0,0);
        }
        __syncthreads();
    }

    // ---- epilogue: bias + LSTM + row-sum reduce (reuse As as rowsum) ----
    float* rowsum = &As[0];
    if(tid<BM) rowsum[tid]=0.f;
    __syncthreads();
    int d = w*32+l31;
    float bi=b_ih[d]+b_hh[d];
    float bg=b_ih[256+d]+b_hh[256+d];
    float bo=b_ih[384+d]+b_hh[384+d];
#pragma unroll
    for(int m=0;m<2;m++){
#pragma unroll
        for(int r=0;r<16;r++){
            int row = m*32 + (r&3)+8*(r>>2)+4*lh;
            float ig = acc[m][0][r] + bi;
            float gg = acc[m][1][r] + bg;
            float og = acc[m][2][r] + bo;
            float cc = sigf(ig)*tanhfast(gg);
            float ov = sigf(og)*tanhfast(cc);
#pragma unroll
            for(int off=1; off<32; off<<=1) ov += __shfl_xor(ov, off, 64);
            if(l31==0) atomicAdd(&rowsum[row], ov);
        }
    }
    __syncthreads();
    if(tid < BM){
        int t = t0 + tid;
        if(t < T) score[t] = sigf(rowsum[tid]);
    }
}

extern "C" void kernel_launch(void* const* d_in, const int* in_sizes, int n_in,
                              void* d_out, int out_size, void* d_ws, size_t ws_size,
                              hipStream_t stream){
    const float* x    = (const float*)d_in[0];
    const float* remb = (const float*)d_in[1];
    const float* W1   = (const float*)d_in[2];
    const float* b1   = (const float*)d_in[3];
    const float* W2   = (const float*)d_in[4];
    const float* b2   = (const float*)d_in[5];
    const float* Wih  = (const float*)d_in[6];
    const float* b_ih = (const float*)d_in[8];
    const float* b_hh = (const float*)d_in[9];
    const int*   ei   = (const int*)d_in[10];
    const int*   trip = (const int*)d_in[11];
    float* score = (float*)d_out;

    const int N = in_sizes[0]/NF;       // 15000
    const int E = in_sizes[10]/2;       // 200000
    const int T = in_sizes[11]/3;       // 100000
    const int* src = ei;
    const int* dst = ei + E;

    float* ws = (float*)d_ws;
    size_t o = 0;
    ushort* img  = (ushort*)(ws+o); o += (size_t)12*64*64*8/2;   // 786 KB
    float* zbf   = ws+o;            o += (size_t)N*D2;           // fp32 z, 7.7 MB
    int*   cnt    = (int*)(ws+o);   o += (size_t)((N+8)&~7);
    int*   rowptr = (int*)(ws+o);   o += (size_t)((N+8)&~7);
    int*   rowcur = (int*)(ws+o);   o += (size_t)((N+8)&~7);
    int*   esrc   = (int*)(ws+o);   o += (size_t)E;
    float* enorm  = ws+o;           o += (size_t)E;
    float* dinv   = ws+o;           o += (size_t)((N+7)&~7);
    float* h1     = ws+o;           o += (size_t)N*D1;
    float* hbuf   = ws+o;           o += (size_t)N*D1;
    float* hz     = ws+o;           o += (size_t)N*D2;
    (void)ws_size; (void)n_in; (void)out_size;

    hipMemsetAsync(cnt, 0, (size_t)N*sizeof(int), stream);

    k_wimgB<<<dim3((12*64*64+255)/256), dim3(256), 0, stream>>>(Wih, img);
    k_deg  <<<dim3((E+255)/256), dim3(256), 0, stream>>>(dst, cnt, E);
    k_scan <<<dim3(1), dim3(256), 0, stream>>>(cnt, rowptr, rowcur, dinv, N, E);
    k_fill <<<dim3((E+255)/256), dim3(256), 0, stream>>>(src, dst, dinv, rowcur, esrc, enorm, E);
    k_h1   <<<dim3((N+3)/4), dim3(256), 0, stream>>>(x, W1, h1, N);
    k_gath1<<<dim3((N+3)/4), dim3(256), 0, stream>>>(h1, rowptr, esrc, enorm, dinv, b1, hbuf, N);
    k_hz   <<<dim3(N), dim3(128), 0, stream>>>(hbuf, W2, hz, N);
    k_gath2<<<dim3(N), dim3(128), 0, stream>>>(hz, rowptr, esrc, enorm, dinv, b2, zbf, N);
    k_big  <<<dim3((T+BM-1)/BM), dim3(256), 0, stream>>>(remb, img, zbf, b_ih, b_hh, trip, score, T);
}